// Round 8
// baseline (85.404 us; speedup 1.0000x reference)
//
#include <hip/hip_runtime.h>
#include <math.h>

#define BB 16
#define SS 2048
#define HH 2
#define ROWS_PER_BLOCK 128
#define THREADS1 512          // 8 waves; wave owns one 16-row tile
#define NSUP (SS / 32)        // 64 superiters, 2 key-tiles each
#define KVT_STRIDE 2080       // halves; 4160B row stride (16B-aligned, bank-skewed)

typedef _Float16 half8 __attribute__((ext_vector_type(8)));
typedef _Float16 half4h __attribute__((ext_vector_type(4)));
typedef _Float16 half2h __attribute__((ext_vector_type(2)));
typedef float floatx4 __attribute__((ext_vector_type(4)));

__device__ __forceinline__ float fast_exp2(float x) {
  return __builtin_amdgcn_exp2f(x);
}
__device__ __forceinline__ half2h pkrtz(float a, float b) {
  return __builtin_bit_cast(half2h, __builtin_amdgcn_cvt_pkrtz(a, b));
}

// Fused. grid: [b(16)][h(2)][rb(16)] = 512 blocks of 512 thr (8 waves).
// Wave wv sweeps rows [rb*128+wv*16,+16) x all 2048 keys.
// Inner superiter = 2 key-tiles in batched phases (reads->QK->exp->pack->PV)
// so ~4 tiles are in flight per wave: hides MFMA->VALU and LDS latency.
__global__ __launch_bounds__(THREADS1, 4)
void qattn_fused(const float* __restrict__ x,
                 const float* __restrict__ theta,
                 const float* __restrict__ w_out,
                 const float* __restrict__ b_out,
                 float* __restrict__ out) {
  __shared__ half4h s_keys[SS];              // [key][wire0-3] f16 (16 KB)
  __shared__ _Float16 s_kvT[5 * KVT_STRIDE]; // rows 0-3 = kv^T, row 4 = ones (20.3 KB)
  __shared__ float po[ROWS_PER_BLOCK * 6];   // per-row o[4],l (3 KB)

  const int bid = blockIdx.x;
  const int rb  = bid & 15;
  const int h   = (bid >> 4) & 1;
  const int b   = bid >> 5;
  const int t   = threadIdx.x;

  const float4 th = ((const float4*)theta)[h];
  const float4* xb = (const float4*)x;       // element (b*SS+s)*2 + h

  // --- stage cos(x+theta) f16: key rows + kv^T + ones row ---
  for (int s = t; s < SS; s += THREADS1) {
    float4 xr = xb[(size_t)(b * SS + s) * 2 + h];
    float c0 = __cosf(xr.x + th.x), c1 = __cosf(xr.y + th.y);
    float c2 = __cosf(xr.z + th.z), c3 = __cosf(xr.w + th.w);
    half4h v = {(_Float16)c0, (_Float16)c1, (_Float16)c2, (_Float16)c3};
    s_keys[s] = v;
    s_kvT[0 * KVT_STRIDE + s] = (_Float16)c0;
    s_kvT[1 * KVT_STRIDE + s] = (_Float16)c1;
    s_kvT[2 * KVT_STRIDE + s] = (_Float16)c2;
    s_kvT[3 * KVT_STRIDE + s] = (_Float16)c3;
  }
  for (int i = t; i < KVT_STRIDE; i += THREADS1)
    s_kvT[4 * KVT_STRIDE + i] = (_Float16)1.0f;   // ones -> denominator col
  __syncthreads();

  const int lane = t & 63;
  const int wv   = t >> 6;        // wave id 0..7 -> 16-row tile
  const int quad = lane >> 4;
  const int l15  = lane & 15;

  // QK B-operand (wave's 16 query rows * 0.5*log2e); nonzero only quad 0, k<4
  const float KS  = 0.72134752044448170367f;
  const float scl = (lane < 16) ? KS : 0.0f;
  half4h rq = s_keys[rb * ROWS_PER_BLOCK + wv * 16 + l15];
  const _Float16 z = (_Float16)0.0f;
  half8 bq = {(_Float16)((float)rq[0] * scl), (_Float16)((float)rq[1] * scl),
              (_Float16)((float)rq[2] * scl), (_Float16)((float)rq[3] * scl),
              z, z, z, z};

  // PV B-operand source: row min(l15,4) of kv^T, 4 consecutive keys at 4*quad
  const _Float16* bb = s_kvT + (l15 < 4 ? l15 : 4) * KVT_STRIDE + quad * 4;

  floatx4 o = {0.f, 0.f, 0.f, 0.f};
  const floatx4 zf = {0.f, 0.f, 0.f, 0.f};

#pragma unroll 2
  for (int it = 0; it < NSUP; ++it) {
    const int k0 = it * 32;
    // ---- phase 1: all LDS reads for both tiles ----
    half4h a0v = s_keys[k0 + l15];
    half4h a1v = s_keys[k0 + 16 + l15];
    half4h bl0 = *(const half4h*)(bb + k0);
    half4h bl1 = *(const half4h*)(bb + k0 + 16);
    half8 a0 = {a0v[0], a0v[1], a0v[2], a0v[3], z, z, z, z};
    half8 a1 = {a1v[0], a1v[1], a1v[2], a1v[3], z, z, z, z};
    half8 bpv0 = {bl0[0], bl0[1], bl0[2], bl0[3], z, z, z, z};
    half8 bpv1 = {bl1[0], bl1[1], bl1[2], bl1[3], z, z, z, z};

    // ---- phase 2: both QK MFMAs (independent) ----
    floatx4 c0 = __builtin_amdgcn_mfma_f32_16x16x32_f16(a0, bq, zf, 0, 0, 0);
    floatx4 c1 = __builtin_amdgcn_mfma_f32_16x16x32_f16(a1, bq, zf, 0, 0, 0);

    // ---- phase 3: 8 independent exps, 4 pkrtz ----
    float e00 = fast_exp2(c0[0]), e01 = fast_exp2(c0[1]);
    float e02 = fast_exp2(c0[2]), e03 = fast_exp2(c0[3]);
    float e10 = fast_exp2(c1[0]), e11 = fast_exp2(c1[1]);
    float e12 = fast_exp2(c1[2]), e13 = fast_exp2(c1[3]);
    half2h p00 = pkrtz(e00, e01), p01 = pkrtz(e02, e03);
    half2h p10 = pkrtz(e10, e11), p11 = pkrtz(e12, e13);
    half8 apv0 = {p00[0], p00[1], p01[0], p01[1], z, z, z, z};
    half8 apv1 = {p10[0], p10[1], p11[0], p11[1], z, z, z, z};

    // ---- phase 4: both PV MFMAs (accumulate chain pipelines) ----
    o = __builtin_amdgcn_mfma_f32_16x16x32_f16(apv0, bpv0, o, 0, 0, 0);
    o = __builtin_amdgcn_mfma_f32_16x16x32_f16(apv1, bpv1, o, 0, 0, 0);
  }

  // D[m=row quad*4+reg][n=l15]: n 0-3 = numerator wires, n==4 = l
  if (l15 < 5) {
#pragma unroll
    for (int r = 0; r < 4; ++r)
      po[(wv * 16 + quad * 4 + r) * 6 + l15] = o[r];
  }
  __syncthreads();

  // --- normalize + out-projection; atomicAdd merges the two heads ---
  if (t < ROWS_PER_BLOCK * 4) {
    const int row = t >> 2;           // 0..127
    const int ep  = (t & 3) * 2;      // output cols {ep, ep+1}
    const float* pr = po + row * 6;
    const float inv = 1.0f / pr[4];
    const float o0 = pr[0] * inv, o1 = pr[1] * inv,
                o2 = pr[2] * inv, o3 = pr[3] * inv;
    float* op = out + ((size_t)(b * SS + rb * ROWS_PER_BLOCK + row)) * 8;
#pragma unroll
    for (int k = 0; k < 2; ++k) {
      const int e = ep + k;
      const float* wr = w_out + e * 8 + h * 4;
      float val = fmaf(o0, wr[0], fmaf(o1, wr[1], fmaf(o2, wr[2], o3 * wr[3])));
      if (h == 0) val += b_out[e];
      atomicAdd(op + e, val);
    }
  }
}

extern "C" void kernel_launch(void* const* d_in, const int* in_sizes, int n_in,
                              void* d_out, int out_size, void* d_ws, size_t ws_size,
                              hipStream_t stream) {
  const float* x     = (const float*)d_in[0];
  const float* theta = (const float*)d_in[1];
  const float* w_out = (const float*)d_in[2];
  const float* b_out = (const float*)d_in[3];
  float* out = (float*)d_out;
  (void)in_sizes; (void)n_in; (void)d_ws; (void)ws_size;

  (void)hipMemsetAsync(d_out, 0, (size_t)out_size * sizeof(float), stream);
  qattn_fused<<<dim3(BB * HH * 16), THREADS1, 0, stream>>>(x, theta, w_out, b_out, out);
}

// Round 9
// 80.542 us; speedup vs baseline: 1.0604x; 1.0604x over previous
//
#include <hip/hip_runtime.h>
#include <math.h>

#define BB 16
#define SS 2048
#define HH 2
#define RPB 128               // rows per block
#define THREADS 1024          // 16 waves = 8 row-tiles x 2 key-halves
#define KHALF (SS / 2)        // 1024 keys per wave
#define NITER (KHALF / 16)    // 64
#define KVT_STRIDE 2064       // 4128B row stride: rows 8 banks apart (2-way max = free)

typedef _Float16 half8 __attribute__((ext_vector_type(8)));
typedef _Float16 half4h __attribute__((ext_vector_type(4)));
typedef _Float16 half2h __attribute__((ext_vector_type(2)));
typedef float floatx4 __attribute__((ext_vector_type(4)));

__device__ __forceinline__ float fast_exp2(float x) {
  return __builtin_amdgcn_exp2f(x);
}
__device__ __forceinline__ half2h pkrtz(float a, float b) {
  return __builtin_bit_cast(half2h, __builtin_amdgcn_cvt_pkrtz(a, b));
}

// grid [b(16)][h(2)][rb(16)] = 512 blocks of 1024 thr (16 waves) -> 2 blocks/CU,
// 32 waves/CU = 8/SIMD (full occupancy; VGPR<=64 via launch_bounds).
// Wave (tile, hf): rows [rb*128 + tile*16, +16) x keys [hf*1024, +1024).
// QK via 16x16x32 MFMA; exp2 on VALU; PV via MFMA with ones-column giving the
// softmax denominator. Key-half partials merged in LDS; out-proj fused;
// heads merged via 2-contributor atomicAdd onto memset-zeroed out.
__global__ __launch_bounds__(THREADS, 8)
void qattn_fused(const float* __restrict__ x,
                 const float* __restrict__ theta,
                 const float* __restrict__ w_out,
                 const float* __restrict__ b_out,
                 float* __restrict__ out) {
  __shared__ half8 s_keys[SS];               // [key][wire0-3,0,0,0,0] (32 KB)
  __shared__ _Float16 s_kvT[5 * KVT_STRIDE]; // rows 0-3 kv^T, row 4 ones (20.6 KB)
  __shared__ float po[RPB * 2 * 5];          // [row][half][o0..3,l] (5 KB)

  const int bid = blockIdx.x;
  const int rb  = bid & 15;
  const int h   = (bid >> 4) & 1;
  const int b   = bid >> 5;
  const int t   = threadIdx.x;

  const float4 th = ((const float4*)theta)[h];
  const float4* xb = (const float4*)x;       // element (b*SS+s)*2 + h

  // --- stage cos(x+theta) f16: key rows (A-layout) + kv^T + ones ---
  for (int s = t; s < SS; s += THREADS) {
    float4 xr = xb[(size_t)(b * SS + s) * 2 + h];
    float c0 = __cosf(xr.x + th.x), c1 = __cosf(xr.y + th.y);
    float c2 = __cosf(xr.z + th.z), c3 = __cosf(xr.w + th.w);
    const _Float16 z = (_Float16)0.0f;
    half8 v = {(_Float16)c0, (_Float16)c1, (_Float16)c2, (_Float16)c3, z, z, z, z};
    s_keys[s] = v;
    s_kvT[0 * KVT_STRIDE + s] = (_Float16)c0;
    s_kvT[1 * KVT_STRIDE + s] = (_Float16)c1;
    s_kvT[2 * KVT_STRIDE + s] = (_Float16)c2;
    s_kvT[3 * KVT_STRIDE + s] = (_Float16)c3;
  }
  for (int i = t; i < KVT_STRIDE; i += THREADS)
    s_kvT[4 * KVT_STRIDE + i] = (_Float16)1.0f;   // ones -> denominator col
  __syncthreads();

  const int lane = t & 63;
  const int wv   = t >> 6;        // 0..15
  const int tile = wv >> 1;       // 0..7  -> 16-row tile
  const int hf   = wv & 1;        // key half
  const int quad = lane >> 4;
  const int l15  = lane & 15;

  // QK B-operand: wave's 16 query rows * 0.5*log2e; nonzero only quad 0, k<4
  const float KS  = 0.72134752044448170367f;
  const float scl = (lane < 16) ? KS : 0.0f;
  half4h rq = *(const half4h*)&s_keys[rb * RPB + tile * 16 + l15];
  const _Float16 z = (_Float16)0.0f;
  half8 bq = {(_Float16)((float)rq[0] * scl), (_Float16)((float)rq[1] * scl),
              (_Float16)((float)rq[2] * scl), (_Float16)((float)rq[3] * scl),
              z, z, z, z};

  // PV B-operand source: row min(l15,4) of kv^T (l15>=5 broadcast of ones row)
  const _Float16* bb = s_kvT + (l15 < 4 ? l15 : 4) * KVT_STRIDE + hf * KHALF + quad * 4;
  const half8* ak = s_keys + hf * KHALF;

  floatx4 o = {0.f, 0.f, 0.f, 0.f};
  const floatx4 zf = {0.f, 0.f, 0.f, 0.f};

#pragma unroll 2
  for (int kt = 0; kt < NITER; ++kt) {
    // QK A: A[m=key l15][k=8q+j], j<4 real, upper half zeros from LDS
    half8 a = ak[kt * 16 + l15];                    // ds_read_b128
    half4h bl = *(const half4h*)(bb + kt * 16);     // ds_read_b64
    half8 bpv = {bl[0], bl[1], bl[2], bl[3], z, z, z, z};

    // scores C[key 4q+reg][row l15], pre-scaled for exp2
    floatx4 c = __builtin_amdgcn_mfma_f32_16x16x32_f16(a, bq, zf, 0, 0, 0);

    // P directly in PV A-operand layout: A[m=l15][k=8q+j] = E[row][key 4q+j]
    half2h p01 = pkrtz(fast_exp2(c[0]), fast_exp2(c[1]));
    half2h p23 = pkrtz(fast_exp2(c[2]), fast_exp2(c[3]));
    half8 apv = {p01[0], p01[1], p23[0], p23[1], z, z, z, z};

    o = __builtin_amdgcn_mfma_f32_16x16x32_f16(apv, bpv, o, 0, 0, 0);
  }

  // D[m=quad*4+reg][n=l15]: n 0-3 numerator wires, n==4 = l
  if (l15 < 5) {
#pragma unroll
    for (int r = 0; r < 4; ++r)
      po[((tile * 16 + quad * 4 + r) * 2 + hf) * 5 + l15] = o[r];
  }
  __syncthreads();

  // --- merge key-halves, normalize, out-project; atomicAdd merges heads ---
  {
    const int row = t >> 3;           // 0..127
    const int e   = t & 7;            // output column
    const float* pr = po + row * 10;
    const float n0 = pr[0] + pr[5];
    const float n1 = pr[1] + pr[6];
    const float n2 = pr[2] + pr[7];
    const float n3 = pr[3] + pr[8];
    const float inv = 1.0f / (pr[4] + pr[9]);
    const float* wr = w_out + e * 8 + h * 4;
    float val = fmaf(n0, wr[0], fmaf(n1, wr[1], fmaf(n2, wr[2], n3 * wr[3]))) * inv;
    if (h == 0) val += b_out[e];
    atomicAdd(out + ((size_t)(b * SS + rb * RPB + row)) * 8 + e, val);
  }
}

extern "C" void kernel_launch(void* const* d_in, const int* in_sizes, int n_in,
                              void* d_out, int out_size, void* d_ws, size_t ws_size,
                              hipStream_t stream) {
  const float* x     = (const float*)d_in[0];
  const float* theta = (const float*)d_in[1];
  const float* w_out = (const float*)d_in[2];
  const float* b_out = (const float*)d_in[3];
  float* out = (float*)d_out;
  (void)in_sizes; (void)n_in; (void)d_ws; (void)ws_size;

  (void)hipMemsetAsync(d_out, 0, (size_t)out_size * sizeof(float), stream);
  qattn_fused<<<dim3(BB * HH * 16), THREADS, 0, stream>>>(x, theta, w_out, b_out, out);
}